// Round 3
// baseline (185.659 us; speedup 1.0000x reference)
//
#include <hip/hip_runtime.h>

#define N_NODES 100000
#define N_EDGES 1600000
#define EPS 1e-5f

typedef __bf16    bf16x8 __attribute__((ext_vector_type(8)));
typedef _Float16  f16x2  __attribute__((ext_vector_type(2)));
typedef _Float16  f16x4  __attribute__((ext_vector_type(4)));
typedef float     f32x4  __attribute__((ext_vector_type(4)));
typedef unsigned int u32;
typedef u32       u32x4  __attribute__((ext_vector_type(4)));

__device__ __forceinline__ u32 pkmax(u32 a, u32 b) {
  u32 d; asm("v_pk_max_f16 %0,%1,%2" : "=v"(d) : "v"(a), "v"(b)); return d;
}
__device__ __forceinline__ u32 pkmin(u32 a, u32 b) {
  u32 d; asm("v_pk_min_f16 %0,%1,%2" : "=v"(d) : "v"(a), "v"(b)); return d;
}
// c + lo(v) + hi(v)   (f16 halves, f32 accumulate)
__device__ __forceinline__ float halves_sum(u32 v, float c) {
  f16x2 p = __builtin_bit_cast(f16x2, v);
#if __has_builtin(__builtin_amdgcn_fdot2)
  f16x2 one2 = {(_Float16)1.0f, (_Float16)1.0f};
  return __builtin_amdgcn_fdot2(p, one2, c, false);
#else
  return c + (float)p[0] + (float)p[1];
#endif
}
// c + lo(v)^2 + hi(v)^2
__device__ __forceinline__ float halves_sq(u32 v, float c) {
  f16x2 p = __builtin_bit_cast(f16x2, v);
#if __has_builtin(__builtin_amdgcn_fdot2)
  return __builtin_amdgcn_fdot2(p, p, c, false);
#else
  float a = (float)p[0], b = (float)p[1];
  return fmaf(a, a, fmaf(b, b, c));
#endif
}

// ---------------------------------------------------------------------------
// Kernel 0: per-node GEMM  g[v] = W_f . feat[v] + W_n . node[v]   (f16 out)
// One wave per 16 nodes. 12 MFMAs per wave. Block 0 also zeroes the 128
// global stats accumulators (safe: only gather_kernel, a later launch,
// writes them).
// ---------------------------------------------------------------------------
__global__ __launch_bounds__(256) void gemm_kernel(
    const float* __restrict__ nodep, const float* __restrict__ feat,
    const float* __restrict__ W, unsigned short* __restrict__ g,
    float* __restrict__ accum) {
  if (blockIdx.x == 0 && threadIdx.x < 128) accum[threadIdx.x] = 0.f;

  const int lane = threadIdx.x & 63;
  const int wave = (int)((blockIdx.x * blockDim.x + threadIdx.x) >> 6);
  const int c    = lane & 15;
  const int quad = lane >> 4;
  if (wave >= N_NODES / 16) return;   // 6250 groups

  bf16x8 Bfrag[4][3];
#pragma unroll
  for (int t = 0; t < 4; ++t) {
    const float* wrow = W + (t * 16 + c) * 67;
#pragma unroll
    for (int s = 0; s < 3; ++s) {
#pragma unroll
      for (int j = 0; j < 8; ++j) {
        int k = s * 32 + quad * 8 + j;
        Bfrag[t][s][j] = (k < 67) ? (__bf16)wrow[k] : (__bf16)0.0f;
      }
    }
  }

  const int v = wave * 16 + c;
  const float* frow = feat + (size_t)v * 64 + quad * 8;
  bf16x8 A0, A1;
#pragma unroll
  for (int j = 0; j < 8; ++j) {
    A0[j] = (__bf16)frow[j];
    A1[j] = (__bf16)frow[32 + j];
  }
  bf16x8 A2;
#pragma unroll
  for (int j = 0; j < 8; ++j) A2[j] = (__bf16)0.0f;
  if (quad == 0) {
    const float* np = nodep + (size_t)v * 3;
    A2[0] = (__bf16)np[0];
    A2[1] = (__bf16)np[1];
    A2[2] = (__bf16)np[2];
  }

#pragma unroll
  for (int t = 0; t < 4; ++t) {
    f32x4 acc = {0.f, 0.f, 0.f, 0.f};
    acc = __builtin_amdgcn_mfma_f32_16x16x32_bf16(A0, Bfrag[t][0], acc, 0, 0, 0);
    acc = __builtin_amdgcn_mfma_f32_16x16x32_bf16(A1, Bfrag[t][1], acc, 0, 0, 0);
    acc = __builtin_amdgcn_mfma_f32_16x16x32_bf16(A2, Bfrag[t][2], acc, 0, 0, 0);
    unsigned short* gp = g + (size_t)(wave * 16 + quad * 4) * 64 + t * 16 + c;
#pragma unroll
    for (int r = 0; r < 4; ++r)
      gp[r * 64] = __builtin_bit_cast(unsigned short, (_Float16)acc[r]);
  }
}

// ---------------------------------------------------------------------------
// Kernel 1: gather-reduce, 2-node unrolled for MLP, stats fused via atomics.
// Per node i: max/min of RAW g[dst] rows (c deferred to finalize), plus
// deferred-c sum/sumsq partials (same algebra as before):
//   sum:   Sigma g - 16*Sigma c_i          (from coord sums L)
//   sumsq: Sigma g^2 - 2*Sigma c_i.S_i + 16*Sigma c_i^2 (coord moments M,
//          per-col contractions nS = Sigma n_a,i * S_i)
// Lane (ch=lane&7, r0=lane>>3) handles rows r0,r0+8, cols ch*8..ch*8+7.
// Pipeline: rows for pair P loaded in iteration P-1; edge indices 2 pairs
// ahead. 4 x 16B row loads in flight per lane.
// Epilogue: per-wave corrected partials -> LDS block reduce -> atomicAdd
// into accum[128] (zeroed by gemm_kernel).
// ---------------------------------------------------------------------------
__global__ __launch_bounds__(256, 4) void gather_kernel(
    const float* __restrict__ nodep, const int* __restrict__ edges,
    const _Float16* __restrict__ g, const float* __restrict__ W,
    _Float16* __restrict__ gmax, _Float16* __restrict__ gmin,
    float* __restrict__ accum, int nwaves) {
  const int lane = threadIdx.x & 63;
  const int wave = (int)((blockIdx.x * blockDim.x + threadIdx.x) >> 6);
  const int ch = lane & 7;
  const int r0 = lane >> 3;
  const int kk = lane & 15;

  float sh[8], sq[8], nxS[8], nyS[8], nzS[8];
#pragma unroll
  for (int j = 0; j < 8; ++j) {
    sh[j] = 0.f; sq[j] = 0.f; nxS[j] = 0.f; nyS[j] = 0.f; nzS[j] = 0.f;
  }
  float Lx = 0.f, Ly = 0.f, Lz = 0.f;
  float Mxx = 0.f, Myy = 0.f, Mzz = 0.f, Mxy = 0.f, Mxz = 0.f, Myz = 0.f;

  // per-node body: reductions + gmax/gmin store for node i with rows (va,vb)
  auto process = [&](int i, const u32x4& va, const u32x4& vb) {
    float nx = nodep[3 * i], ny = nodep[3 * i + 1], nz = nodep[3 * i + 2];
    Lx += nx; Ly += ny; Lz += nz;
    Mxx = fmaf(nx, nx, Mxx); Myy = fmaf(ny, ny, Myy); Mzz = fmaf(nz, nz, Mzz);
    Mxy = fmaf(nx, ny, Mxy); Mxz = fmaf(nx, nz, Mxz); Myz = fmaf(ny, nz, Myz);

    u32 mx[4], mn[4];
#pragma unroll
    for (int q = 0; q < 4; ++q) {
      mx[q] = pkmax(va[q], vb[q]);
      mn[q] = pkmin(va[q], vb[q]);
    }
#pragma unroll
    for (int q = 0; q < 4; ++q) {
      u32 plo = __builtin_amdgcn_perm(va[q], vb[q], 0x01000504u); // col 2q
      u32 phi = __builtin_amdgcn_perm(va[q], vb[q], 0x03020706u); // col 2q+1
      float Slo = halves_sum(plo, 0.f);
      float Shi = halves_sum(phi, 0.f);
      sq[2 * q]     = halves_sq(plo, sq[2 * q]);
      sq[2 * q + 1] = halves_sq(phi, sq[2 * q + 1]);
      sh[2 * q]     += Slo;
      sh[2 * q + 1] += Shi;
      nxS[2 * q]     = fmaf(nx, Slo, nxS[2 * q]);
      nxS[2 * q + 1] = fmaf(nx, Shi, nxS[2 * q + 1]);
      nyS[2 * q]     = fmaf(ny, Slo, nyS[2 * q]);
      nyS[2 * q + 1] = fmaf(ny, Shi, nyS[2 * q + 1]);
      nzS[2 * q]     = fmaf(nz, Slo, nzS[2 * q]);
      nzS[2 * q + 1] = fmaf(nz, Shi, nzS[2 * q + 1]);
    }
#pragma unroll
    for (int s = 8; s < 64; s <<= 1) {
#pragma unroll
      for (int q = 0; q < 4; ++q) {
        mx[q] = pkmax(mx[q], __shfl_xor(mx[q], s, 64));
        mn[q] = pkmin(mn[q], __shfl_xor(mn[q], s, 64));
      }
    }
    if (lane < 8) {   // ch == lane; 16B f16 stores, 8 lanes -> 128B/row
      u32x4 wm = {mx[0], mx[1], mx[2], mx[3]};
      *(u32x4*)(gmax + (size_t)i * 64 + ch * 8) = wm;
      u32x4 wn = {mn[0], mn[1], mn[2], mn[3]};
      *(u32x4*)(gmin + (size_t)i * 64 + ch * 8) = wn;
    }
  };

  const int S2 = 2 * nwaves;
  int iA = wave;            // first node of current pair (always < N at entry)
  int iB = wave + nwaves;   // second node of current pair (guarded)

  // edge indices for pair 0: lanes 0..15 -> node iA, lanes 16..31 -> node iB
  int dcur = 0;
  {
    int node = (lane < 16) ? iA : iB;
    if (lane < 32 && node < N_NODES)
      dcur = edges[2 * (node + kk * N_NODES) + 1];
  }
  // rows for pair 0
  u32x4 va0, vb0, va1, vb1;
  {
    int a0 = __shfl(dcur, r0, 64),      b0 = __shfl(dcur, r0 + 8, 64);
    int a1 = __shfl(dcur, 16 + r0, 64), b1 = __shfl(dcur, 24 + r0, 64);
    va0 = *(const u32x4*)(g + (size_t)a0 * 64 + ch * 8);
    vb0 = *(const u32x4*)(g + (size_t)b0 * 64 + ch * 8);
    va1 = *(const u32x4*)(g + (size_t)a1 * 64 + ch * 8);
    vb1 = *(const u32x4*)(g + (size_t)b1 * 64 + ch * 8);
  }
  // edge indices for pair 1
  int dnxt = 0;
  {
    int node = ((lane < 16) ? iA : iB) + S2;
    if (lane < 32 && node < N_NODES)
      dnxt = edges[2 * (node + kk * N_NODES) + 1];
  }

#pragma unroll 1
  while (iA < N_NODES) {
    // issue next pair's row gathers (index 0 if out of range -> safe)
    int a0 = __shfl(dnxt, r0, 64),      b0 = __shfl(dnxt, r0 + 8, 64);
    int a1 = __shfl(dnxt, 16 + r0, 64), b1 = __shfl(dnxt, 24 + r0, 64);
    u32x4 wa0 = *(const u32x4*)(g + (size_t)a0 * 64 + ch * 8);
    u32x4 wb0 = *(const u32x4*)(g + (size_t)b0 * 64 + ch * 8);
    u32x4 wa1 = *(const u32x4*)(g + (size_t)a1 * 64 + ch * 8);
    u32x4 wb1 = *(const u32x4*)(g + (size_t)b1 * 64 + ch * 8);
    // edge indices two pairs ahead
    int d2 = 0;
    {
      int node = ((lane < 16) ? iA : iB) + 2 * S2;
      if (lane < 32 && node < N_NODES)
        d2 = edges[2 * (node + kk * N_NODES) + 1];
    }
    // process current pair
    process(iA, va0, vb0);
    if (iB < N_NODES) process(iB, va1, vb1);
    // rotate pipeline
    va0 = wa0; vb0 = wb0; va1 = wa1; vb1 = wb1; dnxt = d2;
    iA += S2; iB += S2;
  }

  // --- reduce stats partials across row-lanes (bits 3..5) ---
#pragma unroll
  for (int s = 8; s < 64; s <<= 1) {
#pragma unroll
    for (int j = 0; j < 8; ++j) {
      sh[j]  += __shfl_xor(sh[j], s, 64);
      sq[j]  += __shfl_xor(sq[j], s, 64);
      nxS[j] += __shfl_xor(nxS[j], s, 64);
      nyS[j] += __shfl_xor(nyS[j], s, 64);
      nzS[j] += __shfl_xor(nzS[j], s, 64);
    }
  }

  // --- per-wave corrected values -> LDS block reduce -> global atomics ---
  __shared__ float sred[4][128];
  const int w = (int)(threadIdx.x >> 6);
  if (lane < 8) {
#pragma unroll
    for (int j = 0; j < 8; ++j) {
      int col = ch * 8 + j;
      const float* wr = W + col * 67 + 64;
      float w0 = wr[0], w1 = wr[1], w2 = wr[2];
      float sumc = w0 * Lx + w1 * Ly + w2 * Lz;
      float cS   = w0 * nxS[j] + w1 * nyS[j] + w2 * nzS[j];
      float wMw  = w0 * w0 * Mxx + w1 * w1 * Myy + w2 * w2 * Mzz
                 + 2.f * (w0 * w1 * Mxy + w0 * w2 * Mxz + w1 * w2 * Myz);
      sred[w][col]      = sh[j] - 16.f * sumc;
      sred[w][64 + col] = sq[j] - 2.f * cS + 16.f * wMw;
    }
  }
  __syncthreads();
  const int t = threadIdx.x;
  if (t < 128)
    atomicAdd(accum + t, (sred[0][t] + sred[1][t]) + (sred[2][t] + sred[3][t]));
}

// ---------------------------------------------------------------------------
// Kernel 2: finalize. Each block derives scale/shift from the 128 global
// accumulators (cheap, L2-hot), then handles 4 cols/thread:
// out[i][d] = relu((sel - c_i[d]) * sc[d] + sh[d]); sel = gmax if sc>=0 else
// gmin (relu(affine(.)) monotone per column). gmin lines only fetched for
// columns with sc<0 (exec-masked load).
// ---------------------------------------------------------------------------
__global__ __launch_bounds__(256) void finalize_kernel(
    const _Float16* __restrict__ gmax, const _Float16* __restrict__ gmin,
    const float* __restrict__ accum, const float* __restrict__ gamma,
    const float* __restrict__ beta, const float* __restrict__ nodep,
    const float* __restrict__ W, float* __restrict__ out) {
  __shared__ __align__(16) float ssl[128];
  __shared__ float wnl[192];
  const int t = threadIdx.x;
  if (t < 64) {
    const float inv_ne = 1.0f / (float)N_EDGES;
    float mean = accum[t] * inv_ne;
    float var  = fmaxf(accum[64 + t] * inv_ne - mean * mean, 0.f);
    float sc   = gamma[t] * rsqrtf(var + EPS);
    ssl[t]      = sc;
    ssl[64 + t] = beta[t] - mean * sc;
    wnl[3 * t]     = W[t * 67 + 64];
    wnl[3 * t + 1] = W[t * 67 + 65];
    wnl[3 * t + 2] = W[t * 67 + 66];
  }
  __syncthreads();

  const int idx = (blockIdx.x * 256 + t) * 4;   // < 6,400,000
  const int i = idx >> 6, d0 = idx & 63;
  const float nx = nodep[3 * i], ny = nodep[3 * i + 1], nz = nodep[3 * i + 2];
  f32x4 scv = *(const f32x4*)&ssl[d0];
  bool needmax = (scv[0] >= 0.f) | (scv[1] >= 0.f) | (scv[2] >= 0.f) | (scv[3] >= 0.f);
  bool needmin = (scv[0] < 0.f) | (scv[1] < 0.f) | (scv[2] < 0.f) | (scv[3] < 0.f);
  f16x4 gx = {}, gn = {};
  if (needmax) gx = *(const f16x4*)(gmax + idx);
  if (needmin) gn = *(const f16x4*)(gmin + idx);
  f32x4 o;
#pragma unroll
  for (int j = 0; j < 4; ++j) {
    int d = d0 + j;
    float sc = scv[j], shf = ssl[64 + d];
    float v = (sc >= 0.f) ? (float)gx[j] : (float)gn[j];
    float c = fmaf(wnl[3 * d + 2], nz, fmaf(wnl[3 * d + 1], ny, wnl[3 * d] * nx));
    o[j] = fmaxf(fmaf(v - c, sc, shf), 0.f);
  }
  *(f32x4*)(out + idx) = o;
}

// ---------------------------------------------------------------------------
extern "C" void kernel_launch(void* const* d_in, const int* in_sizes, int n_in,
                              void* d_out, int out_size, void* d_ws, size_t ws_size,
                              hipStream_t stream) {
  const float* nodep = (const float*)d_in[0];
  const float* feat  = (const float*)d_in[1];
  const float* W     = (const float*)d_in[2];
  const float* gamma = (const float*)d_in[3];
  const float* beta  = (const float*)d_in[4];
  const int*   edges = (const int*)d_in[5];

  // workspace layout (16B-aligned; total 38,400,512 B)
  char* ws = (char*)d_ws;
  unsigned short* g = (unsigned short*)ws;                    // 12,800,000 B
  _Float16* gmax = (_Float16*)(ws + 12800000);                // 12,800,000 B
  _Float16* gmin = (_Float16*)(ws + 25600000);                // 12,800,000 B
  float* accum   = (float*)(ws + 38400000);                   //       512 B
  float* out     = (float*)d_out;

  const int nwaves = 8192;   // 2048 blocks x 4 waves

  gemm_kernel<<<1563, 256, 0, stream>>>(nodep, feat, W, g, accum);
  gather_kernel<<<2048, 256, 0, stream>>>(nodep, edges, (const _Float16*)g, W,
                                          gmax, gmin, accum, nwaves);
  finalize_kernel<<<6250, 256, 0, stream>>>(gmax, gmin, accum, gamma, beta,
                                            nodep, W, out);
}

// Round 4
// 150.226 us; speedup vs baseline: 1.2359x; 1.2359x over previous
//
#include <hip/hip_runtime.h>

#define N_NODES 100000
#define N_EDGES 1600000
#define EPS 1e-5f
#define NG 12500          // groups of 8 nodes
#define GWAVES 2048       // gather waves (512 blocks x 4)

typedef __bf16    bf16x8 __attribute__((ext_vector_type(8)));
typedef _Float16  f16x2  __attribute__((ext_vector_type(2)));
typedef _Float16  f16x4  __attribute__((ext_vector_type(4)));
typedef float     f32x4  __attribute__((ext_vector_type(4)));
typedef unsigned int u32;
typedef u32       u32x4  __attribute__((ext_vector_type(4)));

__device__ __forceinline__ u32 pkmax(u32 a, u32 b) {
  u32 d; asm("v_pk_max_f16 %0,%1,%2" : "=v"(d) : "v"(a), "v"(b)); return d;
}
__device__ __forceinline__ u32 pkmin(u32 a, u32 b) {
  u32 d; asm("v_pk_min_f16 %0,%1,%2" : "=v"(d) : "v"(a), "v"(b)); return d;
}
// c + lo(v) + hi(v)   (f16 halves, f32 accumulate)
__device__ __forceinline__ float halves_sum(u32 v, float c) {
  f16x2 p = __builtin_bit_cast(f16x2, v);
#if __has_builtin(__builtin_amdgcn_fdot2)
  f16x2 one2 = {(_Float16)1.0f, (_Float16)1.0f};
  return __builtin_amdgcn_fdot2(p, one2, c, false);
#else
  return c + (float)p[0] + (float)p[1];
#endif
}
// c + lo(v)^2 + hi(v)^2
__device__ __forceinline__ float halves_sq(u32 v, float c) {
  f16x2 p = __builtin_bit_cast(f16x2, v);
#if __has_builtin(__builtin_amdgcn_fdot2)
  return __builtin_amdgcn_fdot2(p, p, c, false);
#else
  float a = (float)p[0], b = (float)p[1];
  return fmaf(a, a, fmaf(b, b, c));
#endif
}

// ---------------------------------------------------------------------------
// Kernel 0: per-node GEMM  g[v] = W_f . feat[v] + W_n . node[v]   (f16 out)
// One wave per 16 nodes, 12 MFMAs. f32x4 feature loads (G13). Block 0 zeroes
// the 128 global stats accumulators (gather, launched later, adds into them).
// ---------------------------------------------------------------------------
__global__ __launch_bounds__(256) void gemm_kernel(
    const float* __restrict__ nodep, const float* __restrict__ feat,
    const float* __restrict__ W, unsigned short* __restrict__ g,
    float* __restrict__ accum) {
  if (blockIdx.x == 0 && threadIdx.x < 128) accum[threadIdx.x] = 0.f;

  const int lane = threadIdx.x & 63;
  const int wave = (int)((blockIdx.x * blockDim.x + threadIdx.x) >> 6);
  const int c    = lane & 15;
  const int quad = lane >> 4;
  if (wave >= N_NODES / 16) return;   // 6250 groups

  bf16x8 Bfrag[4][3];
#pragma unroll
  for (int t = 0; t < 4; ++t) {
    const float* wrow = W + (t * 16 + c) * 67;
#pragma unroll
    for (int s = 0; s < 3; ++s) {
#pragma unroll
      for (int j = 0; j < 8; ++j) {
        int k = s * 32 + quad * 8 + j;
        Bfrag[t][s][j] = (k < 67) ? (__bf16)wrow[k] : (__bf16)0.0f;
      }
    }
  }

  const int v = wave * 16 + c;
  const f32x4* f4 = (const f32x4*)(feat + (size_t)v * 64 + quad * 8);
  f32x4 fa = f4[0], fb = f4[1];        // cols quad*8 .. quad*8+7
  const f32x4* f4b = (const f32x4*)(feat + (size_t)v * 64 + 32 + quad * 8);
  f32x4 fc = f4b[0], fd = f4b[1];      // cols 32+quad*8 ..
  bf16x8 A0, A1;
#pragma unroll
  for (int j = 0; j < 4; ++j) {
    A0[j] = (__bf16)fa[j]; A0[j + 4] = (__bf16)fb[j];
    A1[j] = (__bf16)fc[j]; A1[j + 4] = (__bf16)fd[j];
  }
  bf16x8 A2;
#pragma unroll
  for (int j = 0; j < 8; ++j) A2[j] = (__bf16)0.0f;
  if (quad == 0) {
    const float* np = nodep + (size_t)v * 3;
    A2[0] = (__bf16)np[0];
    A2[1] = (__bf16)np[1];
    A2[2] = (__bf16)np[2];
  }

#pragma unroll
  for (int t = 0; t < 4; ++t) {
    f32x4 acc = {0.f, 0.f, 0.f, 0.f};
    acc = __builtin_amdgcn_mfma_f32_16x16x32_bf16(A0, Bfrag[t][0], acc, 0, 0, 0);
    acc = __builtin_amdgcn_mfma_f32_16x16x32_bf16(A1, Bfrag[t][1], acc, 0, 0, 0);
    acc = __builtin_amdgcn_mfma_f32_16x16x32_bf16(A2, Bfrag[t][2], acc, 0, 0, 0);
    unsigned short* gp = g + (size_t)(wave * 16 + quad * 4) * 64 + t * 16 + c;
#pragma unroll
    for (int r = 0; r < 4; ++r)
      gp[r * 64] = __builtin_bit_cast(unsigned short, (_Float16)acc[r]);
  }
}

// ---------------------------------------------------------------------------
// Kernel 1: gather-reduce, lane-owns-(node, col-chunk) layout.
// Lane (s=lane>>3, ch=lane&7) owns node i=8*grp+s, cols ch*8..ch*8+7.
// Per group: 16 independent 16B row-gathers per lane; max/min/sum/sumsq
// reduced IN-REGISTER over the 16 edges (no shuffles in the hot loop).
// Deferred-c algebra (c applied in finalize; corrections from coord moments).
// A/B double-buffered groups (static names): gathers issue one process-phase
// ahead, edge indices two phases ahead. gmax/gmin stores fully coalesced.
// Epilogue: shfl-reduce over node-slots (lane bits 3..5), LDS block reduce,
// atomicAdd into accum[128].
// ---------------------------------------------------------------------------
__global__ __launch_bounds__(256) void gather_kernel(
    const float* __restrict__ nodep, const int* __restrict__ edges,
    const _Float16* __restrict__ g, const float* __restrict__ W,
    _Float16* __restrict__ gmax, _Float16* __restrict__ gmin,
    float* __restrict__ accum) {
  const int lane = threadIdx.x & 63;
  const int wave = (int)((blockIdx.x * blockDim.x + threadIdx.x) >> 6);
  const int ch = lane & 7;
  const int s  = lane >> 3;

  float sh[8], sq[8], nxS[8], nyS[8], nzS[8];
#pragma unroll
  for (int j = 0; j < 8; ++j) {
    sh[j] = 0.f; sq[j] = 0.f; nxS[j] = 0.f; nyS[j] = 0.f; nzS[j] = 0.f;
  }
  float Lx = 0.f, Ly = 0.f, Lz = 0.f;
  float Mxx = 0.f, Myy = 0.f, Mzz = 0.f, Mxy = 0.f, Mxz = 0.f, Myz = 0.f;

  int idxA[16], idxB[16];
  u32x4 rA[16], rB[16];
  float cAx, cAy, cAz, cBx, cBy, cBz;

  // load 16 edge-dst indices + node coords for group gx (wave-uniform guard)
#define LOAD_IDX(dst, cx, cy, cz, gx)                                   \
  {                                                                     \
    if ((gx) < NG) {                                                    \
      const int* ep = edges + 16 * (gx) + 2 * s + 1;                    \
      _Pragma("unroll") for (int k = 0; k < 16; ++k)                    \
          dst[k] = ep[2 * k * N_NODES];                                 \
      const float* np = nodep + (size_t)(8 * (gx) + s) * 3;             \
      cx = np[0]; cy = np[1]; cz = np[2];                               \
    } else {                                                            \
      _Pragma("unroll") for (int k = 0; k < 16; ++k) dst[k] = 0;        \
      cx = 0.f; cy = 0.f; cz = 0.f;                                     \
    }                                                                   \
  }

#define GATHER(r, idx)                                                  \
  { _Pragma("unroll") for (int k = 0; k < 16; ++k)                      \
      r[k] = *(const u32x4*)(g + (size_t)idx[k] * 64 + ch * 8); }

  // process group grp with rows r[0..15] and node coords (nx,ny,nz)
  auto process = [&](int grp, const u32x4* r, float nx, float ny, float nz) {
    const int i = 8 * grp + s;
    Lx += nx; Ly += ny; Lz += nz;
    Mxx = fmaf(nx, nx, Mxx); Myy = fmaf(ny, ny, Myy); Mzz = fmaf(nz, nz, Mzz);
    Mxy = fmaf(nx, ny, Mxy); Mxz = fmaf(nx, nz, Mxz); Myz = fmaf(ny, nz, Myz);

    float Sn[8];
#pragma unroll
    for (int j = 0; j < 8; ++j) Sn[j] = 0.f;
    u32 mx[4], mn[4];
#pragma unroll
    for (int p = 0; p < 8; ++p) {
      const u32x4 va = r[2 * p], vb = r[2 * p + 1];
#pragma unroll
      for (int q = 0; q < 4; ++q) {
        u32 m  = pkmax(va[q], vb[q]);
        u32 n2 = pkmin(va[q], vb[q]);
        if (p == 0) { mx[q] = m; mn[q] = n2; }
        else        { mx[q] = pkmax(mx[q], m); mn[q] = pkmin(mn[q], n2); }
        u32 plo = __builtin_amdgcn_perm(va[q], vb[q], 0x01000504u); // col 2q
        u32 phi = __builtin_amdgcn_perm(va[q], vb[q], 0x03020706u); // col 2q+1
        Sn[2 * q]     = halves_sum(plo, Sn[2 * q]);
        Sn[2 * q + 1] = halves_sum(phi, Sn[2 * q + 1]);
        sq[2 * q]     = halves_sq(plo, sq[2 * q]);
        sq[2 * q + 1] = halves_sq(phi, sq[2 * q + 1]);
      }
    }
    u32x4 wm = {mx[0], mx[1], mx[2], mx[3]};
    *(u32x4*)(gmax + (size_t)i * 64 + ch * 8) = wm;
    u32x4 wn = {mn[0], mn[1], mn[2], mn[3]};
    *(u32x4*)(gmin + (size_t)i * 64 + ch * 8) = wn;
#pragma unroll
    for (int j = 0; j < 8; ++j) {
      sh[j]  += Sn[j];
      nxS[j] = fmaf(nx, Sn[j], nxS[j]);
      nyS[j] = fmaf(ny, Sn[j], nyS[j]);
      nzS[j] = fmaf(nz, Sn[j], nzS[j]);
    }
  };

  // ---- prologue ----
  int gA = wave;                    // < GWAVES <= NG, always valid
  LOAD_IDX(idxA, cAx, cAy, cAz, gA);
  GATHER(rA, idxA);
  int gB = gA + GWAVES;
  LOAD_IDX(idxB, cBx, cBy, cBz, gB);

  // ---- main loop: two groups per iteration, static buffers ----
  while (true) {
    GATHER(rB, idxB);                       // rows for gB (row 0 if invalid)
    int gA2 = gB + GWAVES;
    LOAD_IDX(idxA, cAx, cAy, cAz, gA2);     // indices two phases ahead
    float pAx = cAx, pAy = cAy, pAz = cAz;  // (values for gA were consumed
    process(gA, rA, pAx, pAy, pAz);         //  before overwrite? no:)
    if (gB >= NG) break;
    GATHER(rA, idxA);                       // rows for gA2
    int gB2 = gA2 + GWAVES;
    float qBx = cBx, qBy = cBy, qBz = cBz;
    LOAD_IDX(idxB, cBx, cBy, cBz, gB2);
    process(gB, rB, qBx, qBy, qBz);
    if (gA2 >= NG) break;
    gA = gA2; gB = gB2;
  }

  // ---- reduce per-lane partials across node-slot lanes (bits 3..5) ----
#pragma unroll
  for (int step = 8; step < 64; step <<= 1) {
#pragma unroll
    for (int j = 0; j < 8; ++j) {
      sh[j]  += __shfl_xor(sh[j], step, 64);
      sq[j]  += __shfl_xor(sq[j], step, 64);
      nxS[j] += __shfl_xor(nxS[j], step, 64);
      nyS[j] += __shfl_xor(nyS[j], step, 64);
      nzS[j] += __shfl_xor(nzS[j], step, 64);
    }
    Lx  += __shfl_xor(Lx, step, 64);  Ly  += __shfl_xor(Ly, step, 64);
    Lz  += __shfl_xor(Lz, step, 64);
    Mxx += __shfl_xor(Mxx, step, 64); Myy += __shfl_xor(Myy, step, 64);
    Mzz += __shfl_xor(Mzz, step, 64); Mxy += __shfl_xor(Mxy, step, 64);
    Mxz += __shfl_xor(Mxz, step, 64); Myz += __shfl_xor(Myz, step, 64);
  }

  // ---- per-wave corrected values -> LDS block reduce -> global atomics ----
  __shared__ float sred[4][128];
  const int w = (int)(threadIdx.x >> 6);
  if (lane < 8) {
#pragma unroll
    for (int j = 0; j < 8; ++j) {
      int col = ch * 8 + j;
      const float* wr = W + col * 67 + 64;
      float w0 = wr[0], w1 = wr[1], w2 = wr[2];
      float sumc = w0 * Lx + w1 * Ly + w2 * Lz;
      float cS   = w0 * nxS[j] + w1 * nyS[j] + w2 * nzS[j];
      float wMw  = w0 * w0 * Mxx + w1 * w1 * Myy + w2 * w2 * Mzz
                 + 2.f * (w0 * w1 * Mxy + w0 * w2 * Mxz + w1 * w2 * Myz);
      sred[w][col]      = sh[j] - 16.f * sumc;
      sred[w][64 + col] = sq[j] - 2.f * cS + 16.f * wMw;
    }
  }
  __syncthreads();
  const int t = threadIdx.x;
  if (t < 128)
    atomicAdd(accum + t, (sred[0][t] + sred[1][t]) + (sred[2][t] + sred[3][t]));
#undef LOAD_IDX
#undef GATHER
}

// ---------------------------------------------------------------------------
// Kernel 2: finalize. Each block derives scale/shift from the 128 global
// accumulators, then 4 cols/thread:
// out[i][d] = relu((sel - c_i[d]) * sc[d] + sh[d]); sel = gmax if sc>=0 else
// gmin (relu(affine(.)) monotone per column). gmin fetched only if needed.
// ---------------------------------------------------------------------------
__global__ __launch_bounds__(256) void finalize_kernel(
    const _Float16* __restrict__ gmax, const _Float16* __restrict__ gmin,
    const float* __restrict__ accum, const float* __restrict__ gamma,
    const float* __restrict__ beta, const float* __restrict__ nodep,
    const float* __restrict__ W, float* __restrict__ out) {
  __shared__ __align__(16) float ssl[128];
  __shared__ float wnl[192];
  const int t = threadIdx.x;
  if (t < 64) {
    const float inv_ne = 1.0f / (float)N_EDGES;
    float mean = accum[t] * inv_ne;
    float var  = fmaxf(accum[64 + t] * inv_ne - mean * mean, 0.f);
    float sc   = gamma[t] * rsqrtf(var + EPS);
    ssl[t]      = sc;
    ssl[64 + t] = beta[t] - mean * sc;
    wnl[3 * t]     = W[t * 67 + 64];
    wnl[3 * t + 1] = W[t * 67 + 65];
    wnl[3 * t + 2] = W[t * 67 + 66];
  }
  __syncthreads();

  const int idx = (blockIdx.x * 256 + t) * 4;   // < 6,400,000
  const int i = idx >> 6, d0 = idx & 63;
  const float nx = nodep[3 * i], ny = nodep[3 * i + 1], nz = nodep[3 * i + 2];
  f32x4 scv = *(const f32x4*)&ssl[d0];
  bool needmax = (scv[0] >= 0.f) | (scv[1] >= 0.f) | (scv[2] >= 0.f) | (scv[3] >= 0.f);
  bool needmin = (scv[0] < 0.f) | (scv[1] < 0.f) | (scv[2] < 0.f) | (scv[3] < 0.f);
  f16x4 gx = {}, gn = {};
  if (needmax) gx = *(const f16x4*)(gmax + idx);
  if (needmin) gn = *(const f16x4*)(gmin + idx);
  f32x4 o;
#pragma unroll
  for (int j = 0; j < 4; ++j) {
    int d = d0 + j;
    float sc = scv[j], shf = ssl[64 + d];
    float v = (sc >= 0.f) ? (float)gx[j] : (float)gn[j];
    float c = fmaf(wnl[3 * d + 2], nz, fmaf(wnl[3 * d + 1], ny, wnl[3 * d] * nx));
    o[j] = fmaxf(fmaf(v - c, sc, shf), 0.f);
  }
  *(f32x4*)(out + idx) = o;
}

// ---------------------------------------------------------------------------
extern "C" void kernel_launch(void* const* d_in, const int* in_sizes, int n_in,
                              void* d_out, int out_size, void* d_ws, size_t ws_size,
                              hipStream_t stream) {
  const float* nodep = (const float*)d_in[0];
  const float* feat  = (const float*)d_in[1];
  const float* W     = (const float*)d_in[2];
  const float* gamma = (const float*)d_in[3];
  const float* beta  = (const float*)d_in[4];
  const int*   edges = (const int*)d_in[5];

  // workspace layout (16B-aligned; total 38,400,512 B)
  char* ws = (char*)d_ws;
  unsigned short* g = (unsigned short*)ws;                    // 12,800,000 B
  _Float16* gmax = (_Float16*)(ws + 12800000);                // 12,800,000 B
  _Float16* gmin = (_Float16*)(ws + 25600000);                // 12,800,000 B
  float* accum   = (float*)(ws + 38400000);                   //       512 B
  float* out     = (float*)d_out;

  gemm_kernel<<<1563, 256, 0, stream>>>(nodep, feat, W, g, accum);
  gather_kernel<<<512, 256, 0, stream>>>(nodep, edges, (const _Float16*)g, W,
                                         gmax, gmin, accum);
  finalize_kernel<<<6250, 256, 0, stream>>>(gmax, gmin, accum, gamma, beta,
                                            nodep, W, out);
}

// Round 5
// 146.601 us; speedup vs baseline: 1.2664x; 1.0247x over previous
//
#include <hip/hip_runtime.h>

#define N_NODES 100000
#define N_EDGES 1600000
#define EPS 1e-5f
#define NG 12500          // groups of 8 nodes; one wave per group

typedef __bf16    bf16x8 __attribute__((ext_vector_type(8)));
typedef _Float16  f16x2  __attribute__((ext_vector_type(2)));
typedef _Float16  f16x4  __attribute__((ext_vector_type(4)));
typedef float     f32x4  __attribute__((ext_vector_type(4)));
typedef unsigned int u32;
typedef u32       u32x4  __attribute__((ext_vector_type(4)));

__device__ __forceinline__ u32 pkmax(u32 a, u32 b) {
  u32 d; asm("v_pk_max_f16 %0,%1,%2" : "=v"(d) : "v"(a), "v"(b)); return d;
}
__device__ __forceinline__ u32 pkmin(u32 a, u32 b) {
  u32 d; asm("v_pk_min_f16 %0,%1,%2" : "=v"(d) : "v"(a), "v"(b)); return d;
}
// c + lo(v) + hi(v)   (f16 halves, f32 accumulate)
__device__ __forceinline__ float halves_sum(u32 v, float c) {
  f16x2 p = __builtin_bit_cast(f16x2, v);
#if __has_builtin(__builtin_amdgcn_fdot2)
  f16x2 one2 = {(_Float16)1.0f, (_Float16)1.0f};
  return __builtin_amdgcn_fdot2(p, one2, c, false);
#else
  return c + (float)p[0] + (float)p[1];
#endif
}
// c + lo(v)^2 + hi(v)^2
__device__ __forceinline__ float halves_sq(u32 v, float c) {
  f16x2 p = __builtin_bit_cast(f16x2, v);
#if __has_builtin(__builtin_amdgcn_fdot2)
  return __builtin_amdgcn_fdot2(p, p, c, false);
#else
  float a = (float)p[0], b = (float)p[1];
  return fmaf(a, a, fmaf(b, b, c));
#endif
}

// ---------------------------------------------------------------------------
// Kernel 0: per-node GEMM  g[v] = W_f . feat[v] + W_n . node[v]   (f16 out)
// One wave per 16 nodes, 12 MFMAs. Block 0 zeroes the 8x128 replicated
// stats accumulators (gather, launched later, adds into them).
// ---------------------------------------------------------------------------
__global__ __launch_bounds__(256) void gemm_kernel(
    const float* __restrict__ nodep, const float* __restrict__ feat,
    const float* __restrict__ W, unsigned short* __restrict__ g,
    float* __restrict__ accum) {
  if (blockIdx.x == 0) {
    for (int k = threadIdx.x; k < 1024; k += 256) accum[k] = 0.f;
  }

  const int lane = threadIdx.x & 63;
  const int wave = (int)((blockIdx.x * blockDim.x + threadIdx.x) >> 6);
  const int c    = lane & 15;
  const int quad = lane >> 4;
  if (wave >= N_NODES / 16) return;   // 6250 groups

  bf16x8 Bfrag[4][3];
#pragma unroll
  for (int t = 0; t < 4; ++t) {
    const float* wrow = W + (t * 16 + c) * 67;
#pragma unroll
    for (int s = 0; s < 3; ++s) {
#pragma unroll
      for (int j = 0; j < 8; ++j) {
        int k = s * 32 + quad * 8 + j;
        Bfrag[t][s][j] = (k < 67) ? (__bf16)wrow[k] : (__bf16)0.0f;
      }
    }
  }

  const int v = wave * 16 + c;
  const f32x4* f4 = (const f32x4*)(feat + (size_t)v * 64 + quad * 8);
  f32x4 fa = f4[0], fb = f4[1];
  const f32x4* f4b = (const f32x4*)(feat + (size_t)v * 64 + 32 + quad * 8);
  f32x4 fc = f4b[0], fd = f4b[1];
  bf16x8 A0, A1;
#pragma unroll
  for (int j = 0; j < 4; ++j) {
    A0[j] = (__bf16)fa[j]; A0[j + 4] = (__bf16)fb[j];
    A1[j] = (__bf16)fc[j]; A1[j + 4] = (__bf16)fd[j];
  }
  bf16x8 A2;
#pragma unroll
  for (int j = 0; j < 8; ++j) A2[j] = (__bf16)0.0f;
  if (quad == 0) {
    const float* np = nodep + (size_t)v * 3;
    A2[0] = (__bf16)np[0];
    A2[1] = (__bf16)np[1];
    A2[2] = (__bf16)np[2];
  }

#pragma unroll
  for (int t = 0; t < 4; ++t) {
    f32x4 acc = {0.f, 0.f, 0.f, 0.f};
    acc = __builtin_amdgcn_mfma_f32_16x16x32_bf16(A0, Bfrag[t][0], acc, 0, 0, 0);
    acc = __builtin_amdgcn_mfma_f32_16x16x32_bf16(A1, Bfrag[t][1], acc, 0, 0, 0);
    acc = __builtin_amdgcn_mfma_f32_16x16x32_bf16(A2, Bfrag[t][2], acc, 0, 0, 0);
    unsigned short* gp = g + (size_t)(wave * 16 + quad * 4) * 64 + t * 16 + c;
#pragma unroll
    for (int r = 0; r < 4; ++r)
      gp[r * 64] = __builtin_bit_cast(unsigned short, (_Float16)acc[r]);
  }
}

// ---------------------------------------------------------------------------
// Kernel 1: gather-reduce. ONE group of 8 nodes per wave (12500 waves total),
// maximizing TLP for the latency-bound random row gather.
// Lane (s=lane>>3, ch=lane&7) owns node i=8*wave+s, cols ch*8..ch*8+7.
// 16 independent 16B row gathers per lane (8 lanes of an s-group cover one
// full 128B row -> 8 cache lines per gather instruction). max/min/sum/sumsq
// reduced entirely in-register over the 16 edges; deferred-c algebra
// (c applied in finalize; corrections from node-coordinate moments).
// Epilogue: shfl-reduce over node-slot lanes (bits 3..5), LDS block reduce,
// atomicAdd into one of 8 replicated accumulator banks (contention /8).
// ---------------------------------------------------------------------------
__global__ __launch_bounds__(256) void gather_kernel(
    const float* __restrict__ nodep, const int* __restrict__ edges,
    const _Float16* __restrict__ g, const float* __restrict__ W,
    _Float16* __restrict__ gmax, _Float16* __restrict__ gmin,
    float* __restrict__ accum) {
  const int lane = threadIdx.x & 63;
  const int wave = (int)((blockIdx.x * blockDim.x + threadIdx.x) >> 6);
  const int ch = lane & 7;
  const int s  = lane >> 3;
  const int i  = wave * 8 + s;          // grid sized so wave < NG always

  // 16 edge-dst indices for node i (src[e] = e % N => edge k is i + k*N)
  int idx[16];
  const int* ep = edges + 2 * i + 1;
#pragma unroll
  for (int k = 0; k < 16; ++k) idx[k] = ep[2 * k * N_NODES];

  // issue all 16 row gathers (independent; 8-lane groups share rows)
  u32x4 r[16];
#pragma unroll
  for (int k = 0; k < 16; ++k)
    r[k] = *(const u32x4*)(g + (size_t)idx[k] * 64 + ch * 8);

  const float* np = nodep + (size_t)i * 3;
  const float nx = np[0], ny = np[1], nz = np[2];

  // in-register reduce over 16 edges
  float Sn[8], sq[8];
#pragma unroll
  for (int j = 0; j < 8; ++j) { Sn[j] = 0.f; sq[j] = 0.f; }
  u32 mx[4], mn[4];
#pragma unroll
  for (int p = 0; p < 8; ++p) {
    const u32x4 va = r[2 * p], vb = r[2 * p + 1];
#pragma unroll
    for (int q = 0; q < 4; ++q) {
      u32 m  = pkmax(va[q], vb[q]);
      u32 n2 = pkmin(va[q], vb[q]);
      if (p == 0) { mx[q] = m; mn[q] = n2; }
      else        { mx[q] = pkmax(mx[q], m); mn[q] = pkmin(mn[q], n2); }
      u32 plo = __builtin_amdgcn_perm(va[q], vb[q], 0x01000504u); // col 2q
      u32 phi = __builtin_amdgcn_perm(va[q], vb[q], 0x03020706u); // col 2q+1
      Sn[2 * q]     = halves_sum(plo, Sn[2 * q]);
      Sn[2 * q + 1] = halves_sum(phi, Sn[2 * q + 1]);
      sq[2 * q]     = halves_sq(plo, sq[2 * q]);
      sq[2 * q + 1] = halves_sq(phi, sq[2 * q + 1]);
    }
  }
  // coalesced 1KB-per-wave stores
  u32x4 wm = {mx[0], mx[1], mx[2], mx[3]};
  *(u32x4*)(gmax + (size_t)i * 64 + ch * 8) = wm;
  u32x4 wn = {mn[0], mn[1], mn[2], mn[3]};
  *(u32x4*)(gmin + (size_t)i * 64 + ch * 8) = wn;

  // ---- epilogue: reduce stats across node-slot lanes (bits 3..5) ----
  float px[8], py[8], pz[8];
#pragma unroll
  for (int j = 0; j < 8; ++j) {
    px[j] = nx * Sn[j]; py[j] = ny * Sn[j]; pz[j] = nz * Sn[j];
  }
  float Lx = nx, Ly = ny, Lz = nz;
  float Mxx = nx * nx, Myy = ny * ny, Mzz = nz * nz;
  float Mxy = nx * ny, Mxz = nx * nz, Myz = ny * nz;
#pragma unroll
  for (int step = 8; step < 64; step <<= 1) {
#pragma unroll
    for (int j = 0; j < 8; ++j) {
      Sn[j] += __shfl_xor(Sn[j], step, 64);
      sq[j] += __shfl_xor(sq[j], step, 64);
      px[j] += __shfl_xor(px[j], step, 64);
      py[j] += __shfl_xor(py[j], step, 64);
      pz[j] += __shfl_xor(pz[j], step, 64);
    }
    Lx  += __shfl_xor(Lx, step, 64);  Ly  += __shfl_xor(Ly, step, 64);
    Lz  += __shfl_xor(Lz, step, 64);
    Mxx += __shfl_xor(Mxx, step, 64); Myy += __shfl_xor(Myy, step, 64);
    Mzz += __shfl_xor(Mzz, step, 64); Mxy += __shfl_xor(Mxy, step, 64);
    Mxz += __shfl_xor(Mxz, step, 64); Myz += __shfl_xor(Myz, step, 64);
  }

  // ---- per-wave corrected values -> LDS block reduce -> replicated atomics
  __shared__ float sred[4][128];
  const int w = (int)(threadIdx.x >> 6);
  if (lane < 8) {
#pragma unroll
    for (int j = 0; j < 8; ++j) {
      int col = ch * 8 + j;
      const float* wr = W + col * 67 + 64;
      float w0 = wr[0], w1 = wr[1], w2 = wr[2];
      float sumc = w0 * Lx + w1 * Ly + w2 * Lz;
      float cS   = w0 * px[j] + w1 * py[j] + w2 * pz[j];
      float wMw  = w0 * w0 * Mxx + w1 * w1 * Myy + w2 * w2 * Mzz
                 + 2.f * (w0 * w1 * Mxy + w0 * w2 * Mxz + w1 * w2 * Myz);
      sred[w][col]      = Sn[j] - 16.f * sumc;
      sred[w][64 + col] = sq[j] - 2.f * cS + 16.f * wMw;
    }
  }
  __syncthreads();
  const int t = threadIdx.x;
  if (t < 128) {
    float v = (sred[0][t] + sred[1][t]) + (sred[2][t] + sred[3][t]);
    atomicAdd(accum + 128 * (blockIdx.x & 7) + t, v);
  }
}

// ---------------------------------------------------------------------------
// Kernel 2: finalize. Each block derives scale/shift from the 8 replicated
// accumulator banks, then 4 cols/thread:
// out[i][d] = relu((sel - c_i[d]) * sc[d] + sh[d]); sel = gmax if sc>=0 else
// gmin (relu(affine(.)) monotone per column). gmin fetched only if needed.
// ---------------------------------------------------------------------------
__global__ __launch_bounds__(256) void finalize_kernel(
    const _Float16* __restrict__ gmax, const _Float16* __restrict__ gmin,
    const float* __restrict__ accum, const float* __restrict__ gamma,
    const float* __restrict__ beta, const float* __restrict__ nodep,
    const float* __restrict__ W, float* __restrict__ out) {
  __shared__ __align__(16) float ssl[128];
  __shared__ float wnl[192];
  const int t = threadIdx.x;
  if (t < 64) {
    float a = 0.f, b = 0.f;
#pragma unroll
    for (int rp = 0; rp < 8; ++rp) {
      a += accum[rp * 128 + t];
      b += accum[rp * 128 + 64 + t];
    }
    const float inv_ne = 1.0f / (float)N_EDGES;
    float mean = a * inv_ne;
    float var  = fmaxf(b * inv_ne - mean * mean, 0.f);
    float sc   = gamma[t] * rsqrtf(var + EPS);
    ssl[t]      = sc;
    ssl[64 + t] = beta[t] - mean * sc;
    wnl[3 * t]     = W[t * 67 + 64];
    wnl[3 * t + 1] = W[t * 67 + 65];
    wnl[3 * t + 2] = W[t * 67 + 66];
  }
  __syncthreads();

  const int idx = (blockIdx.x * 256 + t) * 4;   // < 6,400,000
  const int i = idx >> 6, d0 = idx & 63;
  const float nx = nodep[3 * i], ny = nodep[3 * i + 1], nz = nodep[3 * i + 2];
  f32x4 scv = *(const f32x4*)&ssl[d0];
  bool needmax = (scv[0] >= 0.f) | (scv[1] >= 0.f) | (scv[2] >= 0.f) | (scv[3] >= 0.f);
  bool needmin = (scv[0] < 0.f) | (scv[1] < 0.f) | (scv[2] < 0.f) | (scv[3] < 0.f);
  f16x4 gx = {}, gn = {};
  if (needmax) gx = *(const f16x4*)(gmax + idx);
  if (needmin) gn = *(const f16x4*)(gmin + idx);
  f32x4 o;
#pragma unroll
  for (int j = 0; j < 4; ++j) {
    int d = d0 + j;
    float sc = scv[j], shf = ssl[64 + d];
    float v = (sc >= 0.f) ? (float)gx[j] : (float)gn[j];
    float c = fmaf(wnl[3 * d + 2], nz, fmaf(wnl[3 * d + 1], ny, wnl[3 * d] * nx));
    o[j] = fmaxf(fmaf(v - c, sc, shf), 0.f);
  }
  *(f32x4*)(out + idx) = o;
}

// ---------------------------------------------------------------------------
extern "C" void kernel_launch(void* const* d_in, const int* in_sizes, int n_in,
                              void* d_out, int out_size, void* d_ws, size_t ws_size,
                              hipStream_t stream) {
  const float* nodep = (const float*)d_in[0];
  const float* feat  = (const float*)d_in[1];
  const float* W     = (const float*)d_in[2];
  const float* gamma = (const float*)d_in[3];
  const float* beta  = (const float*)d_in[4];
  const int*   edges = (const int*)d_in[5];

  // workspace layout (16B-aligned; total 38,404,096 B)
  char* ws = (char*)d_ws;
  unsigned short* g = (unsigned short*)ws;                    // 12,800,000 B
  _Float16* gmax = (_Float16*)(ws + 12800000);                // 12,800,000 B
  _Float16* gmin = (_Float16*)(ws + 25600000);                // 12,800,000 B
  float* accum   = (float*)(ws + 38400000);                   //     4,096 B
  float* out     = (float*)d_out;

  gemm_kernel<<<1563, 256, 0, stream>>>(nodep, feat, W, g, accum);
  gather_kernel<<<NG / 4, 256, 0, stream>>>(nodep, edges, (const _Float16*)g,
                                            W, gmax, gmin, accum);
  finalize_kernel<<<6250, 256, 0, stream>>>(gmax, gmin, accum, gamma, beta,
                                            nodep, W, out);
}